// Round 11
// baseline (202.574 us; speedup 1.0000x reference)
//
#include <hip/hip_runtime.h>

// Periodogram: out[b,m] = (re^2 + im^2)/N,  re = aC + bS, im = bC - aS
// r11: Karatsuba 3-MFMA complex product:
//   P1 = sum aC, P2 = sum bS, P3 = sum (a+b)(C-S)
//   re = P1 + P2, im = P3 - P1 + P2
// 48 MFMAs/wave-step (was 64), no dependent accumulator pairs.
// Trig B-operand generated in registers (depth-2 rotation recurrence);
// LDS holds A | B | P=A+B (24 KB), XOR-swizzled conflict-free cells.

typedef __fp16 half8  __attribute__((ext_vector_type(8)));
typedef __fp16 half2v __attribute__((ext_vector_type(2)));
typedef float  f32x4  __attribute__((ext_vector_type(4)));

#define B_SZ 512
#define N_SZ 1024
#define M_SZ 16384
#define BT 128
#define MT 128
#define KT 32

union U2 { half2v h2[2]; uint2 u; };
union BF { half2v h2[4]; half8 v; uint4 u; };

__global__ __launch_bounds__(256, 2)
void periodogram_kernel(const float* __restrict__ x, const float* __restrict__ xgrid,
                        float* __restrict__ out) {
    __shared__ __align__(16) unsigned char smem[3 * 8192];   // A | B | P
    const int tid  = (int)threadIdx.x;
    const int lane = tid & 63;
    const int w    = tid >> 6;
    const int bid  = (int)blockIdx.x;
    const int b0 = (bid & 3) * BT;
    const int m0 = (bid >> 2) * MT;

    const int wr = (w >> 1) * 64;   // wave row offset in tile
    const int wc = (w & 1) * 64;    // wave col offset in tile

    // ---- staging assignment: thread -> rows {row8+32*rep}, k-chunk kk ----
    const int row8 = tid >> 3;          // 0..31
    const int kk   = (tid & 7) * 4;     // 0,4,...,28
    const int g    = kk >> 3;           // 0..3
    const int kkh  = (kk >> 2) & 1;     // 8B half of the 16B cell

    unsigned woff[4];
    const float* srcA[4];
#pragma unroll
    for (int rep = 0; rep < 4; ++rep) {
        const int row = row8 + rep * 32;
        const int rb = row >> 4, r16 = row & 15;
        woff[rep] = (unsigned)(rb * 1024 + ((g * 16 + (r16 ^ (g << 1))) << 4) + kkh * 8);
        srcA[rep] = x + (size_t)(b0 + row) * 2048 + kk;
    }

    // ---- per-lane trig state for the B operand (register-resident) ----
    // lane holds col = wc + fn*16 + (lane&15), k = g8 + j (g8 = (lane>>4)*8),
    // advanced by 32 per K-step. Packed-f16 rotation constants for j=0..7.
    half2v PC[4][4], PS[4][4];
    float c0v[4], s0v[4], C32[4], S32[4];
    const float g8f = (float)((lane >> 4) << 3);
#pragma unroll
    for (int fn = 0; fn < 4; ++fn) {
        const float xg = xgrid[m0 + wc + fn * 16 + (lane & 15)];
        float Cj[8], Sj[8];
        Cj[0] = 1.0f; Sj[0] = 0.0f;
#pragma unroll
        for (int j = 1; j < 8; ++j) {
            float p = xg * (float)j; p -= floorf(p);
            Cj[j] = __builtin_amdgcn_cosf(p);   // cos(2*pi*p)
            Sj[j] = __builtin_amdgcn_sinf(p);
        }
#pragma unroll
        for (int i = 0; i < 4; ++i) {
            PC[fn][i] = __builtin_amdgcn_cvt_pkrtz(Cj[2 * i], Cj[2 * i + 1]);
            PS[fn][i] = __builtin_amdgcn_cvt_pkrtz(Sj[2 * i], Sj[2 * i + 1]);
        }
        float p32 = xg * 32.0f; p32 -= floorf(p32);      // exact product
        C32[fn] = __builtin_amdgcn_cosf(p32);
        S32[fn] = __builtin_amdgcn_sinf(p32);
        float pb = xg * g8f; pb -= floorf(pb);
        c0v[fn] = __builtin_amdgcn_cosf(pb);
        s0v[fn] = __builtin_amdgcn_sinf(pb);
    }

    f32x4 accP1[4][4], accP2[4][4], accP3[4][4];
#pragma unroll
    for (int i = 0; i < 4; ++i)
#pragma unroll
        for (int j = 0; j < 4; ++j) {
            accP1[i][j] = (f32x4)0.0f; accP2[i][j] = (f32x4)0.0f; accP3[i][j] = (f32x4)0.0f;
        }

    // ---- fragment read bases (swizzled lane->cell) ----
    const unsigned roff  = (unsigned)((lane ^ ((lane >> 4) << 1)) << 4);
    const unsigned aBase = 0u     + ((unsigned)(wr >> 4) << 10) + roff;
    const unsigned bBase = 8192u  + ((unsigned)(wr >> 4) << 10) + roff;
    const unsigned pBase = 16384u + ((unsigned)(wr >> 4) << 10) + roff;

    for (int t = 0; t < N_SZ / KT; ++t) {
        const int k0 = t * KT;
        // ---- issue A/B global loads (f32) before the barrier ----
        float4 va[4], vb[4];
#pragma unroll
        for (int rep = 0; rep < 4; ++rep) {
            va[rep] = *(const float4*)(srcA[rep] + k0);
            vb[rep] = *(const float4*)(srcA[rep] + k0 + 1024);
        }
        __syncthreads();   // previous iteration's fragment reads done
        // ---- stage A, B, P=A+B to LDS as f16 ----
#pragma unroll
        for (int rep = 0; rep < 4; ++rep) {
            U2 pa, pb, pp;
            pa.h2[0] = __builtin_amdgcn_cvt_pkrtz(va[rep].x, va[rep].y);
            pa.h2[1] = __builtin_amdgcn_cvt_pkrtz(va[rep].z, va[rep].w);
            pb.h2[0] = __builtin_amdgcn_cvt_pkrtz(vb[rep].x, vb[rep].y);
            pb.h2[1] = __builtin_amdgcn_cvt_pkrtz(vb[rep].z, vb[rep].w);
            pp.h2[0] = __builtin_amdgcn_cvt_pkrtz(va[rep].x + vb[rep].x, va[rep].y + vb[rep].y);
            pp.h2[1] = __builtin_amdgcn_cvt_pkrtz(va[rep].z + vb[rep].z, va[rep].w + vb[rep].w);
            *(uint2*)(smem + 0     + woff[rep]) = pa.u;
            *(uint2*)(smem + 8192  + woff[rep]) = pb.u;
            *(uint2*)(smem + 16384 + woff[rep]) = pp.u;
        }
        __syncthreads();
        // ---- compute: A/B/P from LDS, trig generated in-register ----
        half8 fa[4], fb[4], fp[4];
#pragma unroll
        for (int fm = 0; fm < 4; ++fm) {
            fa[fm] = *(const half8*)(smem + aBase + fm * 1024);
            fb[fm] = *(const half8*)(smem + bBase + fm * 1024);
            fp[fm] = *(const half8*)(smem + pBase + fm * 1024);
        }
#pragma unroll
        for (int fn = 0; fn < 4; ++fn) {
            const float c0 = c0v[fn], s0 = s0v[fn];
            const half2v c0b = __builtin_amdgcn_cvt_pkrtz(c0, c0);
            const half2v s0b = __builtin_amdgcn_cvt_pkrtz(s0, s0);
            BF fc, fs, fd;
#pragma unroll
            for (int i = 0; i < 4; ++i) {
                fc.h2[i] = c0b * PC[fn][i] - s0b * PS[fn][i];
                fs.h2[i] = s0b * PC[fn][i] + c0b * PS[fn][i];
                fd.h2[i] = fc.h2[i] - fs.h2[i];              // C - S
            }
#pragma unroll
            for (int fm = 0; fm < 4; ++fm) {
                accP1[fm][fn] = __builtin_amdgcn_mfma_f32_16x16x32_f16(fa[fm], fc.v, accP1[fm][fn], 0, 0, 0);
                accP2[fm][fn] = __builtin_amdgcn_mfma_f32_16x16x32_f16(fb[fm], fs.v, accP2[fm][fn], 0, 0, 0);
                accP3[fm][fn] = __builtin_amdgcn_mfma_f32_16x16x32_f16(fp[fm], fd.v, accP3[fm][fn], 0, 0, 0);
            }
            // advance base state by Delta-k = 32 (f32, depth-2)
            c0v[fn] = __builtin_fmaf(c0, C32[fn], -(s0 * S32[fn]));
            s0v[fn] = __builtin_fmaf(s0, C32[fn],  (c0 * S32[fn]));
        }
    }

    // ---- epilogue: re = P1+P2, im = P3-P1+P2, out = (re^2+im^2)/N ----
    // D frag layout (measured m89): col = lane&15, row = (lane>>4)*4 + reg
    const float inv = 1.0f / (float)N_SZ;
    const int orow0 = b0 + wr + ((lane >> 4) << 2);
    const int ocol0 = m0 + wc + (lane & 15);
#pragma unroll
    for (int fm = 0; fm < 4; ++fm)
#pragma unroll
        for (int fn = 0; fn < 4; ++fn) {
            const f32x4 p1 = accP1[fm][fn];
            const f32x4 p2 = accP2[fm][fn];
            const f32x4 p3 = accP3[fm][fn];
            const int col = ocol0 + fn * 16;
#pragma unroll
            for (int j = 0; j < 4; ++j) {
                const float re = p1[j] + p2[j];
                const float im = p3[j] - p1[j] + p2[j];
                const int row = orow0 + fm * 16 + j;
                out[(size_t)row * M_SZ + col] = (re * re + im * im) * inv;
            }
        }
}

extern "C" void kernel_launch(void* const* d_in, const int* in_sizes, int n_in,
                              void* d_out, int out_size, void* d_ws, size_t ws_size,
                              hipStream_t stream) {
    const float* x     = (const float*)d_in[0];
    const float* xgrid = (const float*)d_in[1];
    float* out = (float*)d_out;
    dim3 grid(B_SZ / BT * (M_SZ / MT));   // 4 * 128 = 512 blocks
    dim3 block(256);
    periodogram_kernel<<<grid, block, 0, stream>>>(x, xgrid, out);
}

// Round 12
// 104.503 us; speedup vs baseline: 1.9384x; 1.9384x over previous
//
#include <hip/hip_runtime.h>

// Periodogram: out[b,m] = (re^2 + im^2)/N,  re = aC + bS, im = bC - aS
// f16 MFMA GEMMs; trig B-operand generated in registers (depth-2 rotation).
// r12: tile 128x64, grid 1024 -> 4 independent blocks/CU (4 waves/SIMD),
// breaking the 2-block barrier-lockstep that serialized VALU and MFMA phases.
// Wave = 64x32 sub-tile (fm=4, fn=2), acc = 64 VGPR, no spill.

typedef __fp16 half8  __attribute__((ext_vector_type(8)));
typedef __fp16 half2v __attribute__((ext_vector_type(2)));
typedef float  f32x4  __attribute__((ext_vector_type(4)));

#define B_SZ 512
#define N_SZ 1024
#define M_SZ 16384
#define BT 128
#define MT 64
#define KT 32

union U2 { half2v h2[2]; uint2 u; };
union BF { half2v h2[4]; half8 v; uint4 u; };

__global__ __launch_bounds__(256, 4)
void periodogram_kernel(const float* __restrict__ x, const float* __restrict__ xgrid,
                        float* __restrict__ out) {
    __shared__ __align__(16) unsigned char smem[2 * 8192];   // A | B
    const int tid  = (int)threadIdx.x;
    const int lane = tid & 63;
    const int w    = tid >> 6;
    const int bid  = (int)blockIdx.x;
    const int b0 = (bid & 3) * BT;
    const int m0 = (bid >> 2) * MT;

    const int wr = (w >> 1) * 64;   // wave row offset in tile
    const int wc = (w & 1) * 32;    // wave col offset in tile

    // ---- staging assignment: thread -> rows {row8+32*rep}, k-chunk kk ----
    const int row8 = tid >> 3;          // 0..31
    const int kk   = (tid & 7) * 4;     // 0,4,...,28
    const int g    = kk >> 3;           // 0..3
    const int kkh  = (kk >> 2) & 1;     // 8B half of the 16B cell

    unsigned woff[4];
    const float* srcA[4];
#pragma unroll
    for (int rep = 0; rep < 4; ++rep) {
        const int row = row8 + rep * 32;
        const int rb = row >> 4, r16 = row & 15;
        woff[rep] = (unsigned)(rb * 1024 + ((g * 16 + (r16 ^ (g << 1))) << 4) + kkh * 8);
        srcA[rep] = x + (size_t)(b0 + row) * 2048 + kk;
    }

    // ---- per-lane trig state for the B operand (register-resident) ----
    // lane holds col = wc + fn*16 + (lane&15), k = g8 + j (g8 = (lane>>4)*8),
    // advanced by 32 per K-step. Packed-f16 rotation constants for j=0..7.
    half2v PC[2][4], PS[2][4];
    float c0v[2], s0v[2], C32[2], S32[2];
    const float g8f = (float)((lane >> 4) << 3);
#pragma unroll
    for (int fn = 0; fn < 2; ++fn) {
        const float xg = xgrid[m0 + wc + fn * 16 + (lane & 15)];
        float Cj[8], Sj[8];
        Cj[0] = 1.0f; Sj[0] = 0.0f;
#pragma unroll
        for (int j = 1; j < 8; ++j) {
            float p = xg * (float)j; p -= floorf(p);
            Cj[j] = __builtin_amdgcn_cosf(p);   // cos(2*pi*p)
            Sj[j] = __builtin_amdgcn_sinf(p);
        }
#pragma unroll
        for (int i = 0; i < 4; ++i) {
            PC[fn][i] = __builtin_amdgcn_cvt_pkrtz(Cj[2 * i], Cj[2 * i + 1]);
            PS[fn][i] = __builtin_amdgcn_cvt_pkrtz(Sj[2 * i], Sj[2 * i + 1]);
        }
        float p32 = xg * 32.0f; p32 -= floorf(p32);      // exact product
        C32[fn] = __builtin_amdgcn_cosf(p32);
        S32[fn] = __builtin_amdgcn_sinf(p32);
        float pb = xg * g8f; pb -= floorf(pb);
        c0v[fn] = __builtin_amdgcn_cosf(pb);
        s0v[fn] = __builtin_amdgcn_sinf(pb);
    }

    f32x4 accRe[4][2], accIm[4][2];
#pragma unroll
    for (int i = 0; i < 4; ++i)
#pragma unroll
        for (int j = 0; j < 2; ++j) { accRe[i][j] = (f32x4)0.0f; accIm[i][j] = (f32x4)0.0f; }

    // ---- fragment read bases (swizzled lane->cell) ----
    const unsigned roff  = (unsigned)((lane ^ ((lane >> 4) << 1)) << 4);
    const unsigned aBase = 0u    + ((unsigned)(wr >> 4) << 10) + roff;
    const unsigned bBase = 8192u + ((unsigned)(wr >> 4) << 10) + roff;

    for (int t = 0; t < N_SZ / KT; ++t) {
        const int k0 = t * KT;
        // ---- issue A/B global loads (f32) before the barrier ----
        float4 va[4], vb[4];
#pragma unroll
        for (int rep = 0; rep < 4; ++rep) {
            va[rep] = *(const float4*)(srcA[rep] + k0);
            vb[rep] = *(const float4*)(srcA[rep] + k0 + 1024);
        }
        __syncthreads();   // previous iteration's fragment reads done
        // ---- stage A/B to LDS as f16 ----
#pragma unroll
        for (int rep = 0; rep < 4; ++rep) {
            U2 pa, pb;
            pa.h2[0] = __builtin_amdgcn_cvt_pkrtz(va[rep].x, va[rep].y);
            pa.h2[1] = __builtin_amdgcn_cvt_pkrtz(va[rep].z, va[rep].w);
            pb.h2[0] = __builtin_amdgcn_cvt_pkrtz(vb[rep].x, vb[rep].y);
            pb.h2[1] = __builtin_amdgcn_cvt_pkrtz(vb[rep].z, vb[rep].w);
            *(uint2*)(smem + 0    + woff[rep]) = pa.u;
            *(uint2*)(smem + 8192 + woff[rep]) = pb.u;
        }
        __syncthreads();
        // ---- compute: A/B from LDS, trig generated in-register ----
        half8 fa[4], fb[4];
#pragma unroll
        for (int fm = 0; fm < 4; ++fm) {
            fa[fm] = *(const half8*)(smem + aBase + fm * 1024);
            fb[fm] = *(const half8*)(smem + bBase + fm * 1024);
        }
#pragma unroll
        for (int fn = 0; fn < 2; ++fn) {
            const float c0 = c0v[fn], s0 = s0v[fn];
            const half2v c0b = __builtin_amdgcn_cvt_pkrtz(c0, c0);
            const half2v s0b = __builtin_amdgcn_cvt_pkrtz(s0, s0);
            BF fc, fs, fns;
#pragma unroll
            for (int i = 0; i < 4; ++i) {
                fc.h2[i] = c0b * PC[fn][i] - s0b * PS[fn][i];   // pk_mul+pk_fma
                fs.h2[i] = s0b * PC[fn][i] + c0b * PS[fn][i];
            }
            fns.u.x = fs.u.x ^ 0x80008000u;
            fns.u.y = fs.u.y ^ 0x80008000u;
            fns.u.z = fs.u.z ^ 0x80008000u;
            fns.u.w = fs.u.w ^ 0x80008000u;
#pragma unroll
            for (int fm = 0; fm < 4; ++fm) {
                accRe[fm][fn] = __builtin_amdgcn_mfma_f32_16x16x32_f16(fa[fm], fc.v,  accRe[fm][fn], 0, 0, 0);
                accRe[fm][fn] = __builtin_amdgcn_mfma_f32_16x16x32_f16(fb[fm], fs.v,  accRe[fm][fn], 0, 0, 0);
                accIm[fm][fn] = __builtin_amdgcn_mfma_f32_16x16x32_f16(fb[fm], fc.v,  accIm[fm][fn], 0, 0, 0);
                accIm[fm][fn] = __builtin_amdgcn_mfma_f32_16x16x32_f16(fa[fm], fns.v, accIm[fm][fn], 0, 0, 0);
            }
            // advance base state by Delta-k = 32 (f32, depth-2)
            c0v[fn] = __builtin_fmaf(c0, C32[fn], -(s0 * S32[fn]));
            s0v[fn] = __builtin_fmaf(s0, C32[fn],  (c0 * S32[fn]));
        }
    }

    // ---- epilogue: out = (re^2 + im^2)/N ----
    // D frag layout (measured m89): col = lane&15, row = (lane>>4)*4 + reg
    const float inv = 1.0f / (float)N_SZ;
    const int orow0 = b0 + wr + ((lane >> 4) << 2);
    const int ocol0 = m0 + wc + (lane & 15);
#pragma unroll
    for (int fm = 0; fm < 4; ++fm)
#pragma unroll
        for (int fn = 0; fn < 2; ++fn) {
            const f32x4 r = accRe[fm][fn];
            const f32x4 im = accIm[fm][fn];
            const int col = ocol0 + fn * 16;
#pragma unroll
            for (int j = 0; j < 4; ++j) {
                const int row = orow0 + fm * 16 + j;
                out[(size_t)row * M_SZ + col] = (r[j] * r[j] + im[j] * im[j]) * inv;
            }
        }
}

extern "C" void kernel_launch(void* const* d_in, const int* in_sizes, int n_in,
                              void* d_out, int out_size, void* d_ws, size_t ws_size,
                              hipStream_t stream) {
    const float* x     = (const float*)d_in[0];
    const float* xgrid = (const float*)d_in[1];
    float* out = (float*)d_out;
    dim3 grid(4 * (M_SZ / MT));   // 4 * 256 = 1024 blocks -> 4 per CU
    dim3 block(256);
    periodogram_kernel<<<grid, block, 0, stream>>>(x, xgrid, out);
}

// Round 13
// 97.943 us; speedup vs baseline: 2.0683x; 1.0670x over previous
//
#include <hip/hip_runtime.h>

// Periodogram: out[b,m] = (re^2 + im^2)/N,  re = aC + bS, im = bC - aS
// f16 MFMA GEMMs; trig B-operand generated in registers (depth-2 rotation).
// r13: geometry amortization. BT=64, MT=256, KT=64, grid 512 (2 blocks/CU).
// Staging per block-step (BT x KT) unchanged vs r10 but MFMA per step 2x,
// barriers halved (16 pairs). LDS 16 KB: A | B, each 4 row-blocks x 2 k-halves.

typedef __fp16 half8  __attribute__((ext_vector_type(8)));
typedef __fp16 half2v __attribute__((ext_vector_type(2)));
typedef float  f32x4  __attribute__((ext_vector_type(4)));

#define B_SZ 512
#define N_SZ 1024
#define M_SZ 16384
#define BT 64
#define MT 256
#define KT 64

union U2 { half2v h2[2]; uint2 u; };
union BF { half2v h2[4]; half8 v; uint4 u; };

__global__ __launch_bounds__(256, 2)
void periodogram_kernel(const float* __restrict__ x, const float* __restrict__ xgrid,
                        float* __restrict__ out) {
    __shared__ __align__(16) unsigned char smem[2 * 8192];   // A | B
    const int tid  = (int)threadIdx.x;
    const int lane = tid & 63;
    const int w    = tid >> 6;
    const int bid  = (int)blockIdx.x;
    const int b0 = (bid & 7) * BT;        // 8 b-tiles of 64
    const int m0 = (bid >> 3) * MT;       // 64 m-tiles of 256

    const int wc = w * 64;                // wave col offset (4 waves x 64 = 256)

    // ---- staging assignment (r10 machinery + kh sub-block) ----
    const int row8 = tid >> 3;            // 0..31
    const int kk   = (tid & 7) * 4;       // 0,4,...,28
    const int g    = kk >> 3;             // 0..3
    const int kkh  = (kk >> 2) & 1;       // 8B half of the 16B cell

    unsigned woff[2][2];
    const float* srcA[2];
#pragma unroll
    for (int rep = 0; rep < 2; ++rep) {
        const int row = row8 + rep * 32;  // 0..63
        const int rb = row >> 4, r16 = row & 15;
        srcA[rep] = x + (size_t)(b0 + row) * 2048 + kk;
#pragma unroll
        for (int kh = 0; kh < 2; ++kh)
            woff[rep][kh] = (unsigned)(rb * 2048 + kh * 1024 +
                                       ((g * 16 + (r16 ^ (g << 1))) << 4) + kkh * 8);
    }

    // ---- per-lane trig state (register-resident B operand) ----
    // lane holds col = wc + fn*16 + (lane&15); k = 32*sub + g8 + j, g8=(lane>>4)*8.
    half2v PC[4][4], PS[4][4];
    float c0v[4], s0v[4], C32[4], S32[4];
    const float g8f = (float)((lane >> 4) << 3);
#pragma unroll
    for (int fn = 0; fn < 4; ++fn) {
        const float xg = xgrid[m0 + wc + fn * 16 + (lane & 15)];
        float Cj[8], Sj[8];
        Cj[0] = 1.0f; Sj[0] = 0.0f;
#pragma unroll
        for (int j = 1; j < 8; ++j) {
            float p = xg * (float)j; p -= floorf(p);
            Cj[j] = __builtin_amdgcn_cosf(p);
            Sj[j] = __builtin_amdgcn_sinf(p);
        }
#pragma unroll
        for (int i = 0; i < 4; ++i) {
            PC[fn][i] = __builtin_amdgcn_cvt_pkrtz(Cj[2 * i], Cj[2 * i + 1]);
            PS[fn][i] = __builtin_amdgcn_cvt_pkrtz(Sj[2 * i], Sj[2 * i + 1]);
        }
        float p32 = xg * 32.0f; p32 -= floorf(p32);
        C32[fn] = __builtin_amdgcn_cosf(p32);
        S32[fn] = __builtin_amdgcn_sinf(p32);
        float pb = xg * g8f; pb -= floorf(pb);
        c0v[fn] = __builtin_amdgcn_cosf(pb);
        s0v[fn] = __builtin_amdgcn_sinf(pb);
    }

    f32x4 accRe[4][4], accIm[4][4];
#pragma unroll
    for (int i = 0; i < 4; ++i)
#pragma unroll
        for (int j = 0; j < 4; ++j) { accRe[i][j] = (f32x4)0.0f; accIm[i][j] = (f32x4)0.0f; }

    // ---- fragment read base (swizzled lane->cell), wr = 0 for all waves ----
    const unsigned roff = (unsigned)((lane ^ ((lane >> 4) << 1)) << 4);

    for (int t = 0; t < N_SZ / KT; ++t) {
        const int k0 = t * KT;
        // ---- issue A/B global loads before the barrier ----
        float4 va[2][2], vb[2][2];
#pragma unroll
        for (int rep = 0; rep < 2; ++rep)
#pragma unroll
            for (int kh = 0; kh < 2; ++kh) {
                va[rep][kh] = *(const float4*)(srcA[rep] + k0 + kh * 32);
                vb[rep][kh] = *(const float4*)(srcA[rep] + k0 + kh * 32 + 1024);
            }
        __syncthreads();   // previous iteration's fragment reads done
        // ---- stage A/B to LDS as f16 ----
#pragma unroll
        for (int rep = 0; rep < 2; ++rep)
#pragma unroll
            for (int kh = 0; kh < 2; ++kh) {
                U2 pa, pb;
                pa.h2[0] = __builtin_amdgcn_cvt_pkrtz(va[rep][kh].x, va[rep][kh].y);
                pa.h2[1] = __builtin_amdgcn_cvt_pkrtz(va[rep][kh].z, va[rep][kh].w);
                pb.h2[0] = __builtin_amdgcn_cvt_pkrtz(vb[rep][kh].x, vb[rep][kh].y);
                pb.h2[1] = __builtin_amdgcn_cvt_pkrtz(vb[rep][kh].z, vb[rep][kh].w);
                *(uint2*)(smem + 0    + woff[rep][kh]) = pa.u;
                *(uint2*)(smem + 8192 + woff[rep][kh]) = pb.u;
            }
        __syncthreads();
        // ---- compute: two K-32 sub-steps from LDS + in-register trig ----
#pragma unroll
        for (int s = 0; s < 2; ++s) {
            half8 fa[4], fb[4];
#pragma unroll
            for (int fm = 0; fm < 4; ++fm) {
                fa[fm] = *(const half8*)(smem + (unsigned)(fm * 2048 + s * 1024) + roff);
                fb[fm] = *(const half8*)(smem + 8192u + (unsigned)(fm * 2048 + s * 1024) + roff);
            }
#pragma unroll
            for (int fn = 0; fn < 4; ++fn) {
                const float c0 = c0v[fn], s0 = s0v[fn];
                const half2v c0b = __builtin_amdgcn_cvt_pkrtz(c0, c0);
                const half2v s0b = __builtin_amdgcn_cvt_pkrtz(s0, s0);
                BF fc, fs, fns;
#pragma unroll
                for (int i = 0; i < 4; ++i) {
                    fc.h2[i] = c0b * PC[fn][i] - s0b * PS[fn][i];
                    fs.h2[i] = s0b * PC[fn][i] + c0b * PS[fn][i];
                }
                fns.u.x = fs.u.x ^ 0x80008000u;
                fns.u.y = fs.u.y ^ 0x80008000u;
                fns.u.z = fs.u.z ^ 0x80008000u;
                fns.u.w = fs.u.w ^ 0x80008000u;
#pragma unroll
                for (int fm = 0; fm < 4; ++fm) {
                    accRe[fm][fn] = __builtin_amdgcn_mfma_f32_16x16x32_f16(fa[fm], fc.v,  accRe[fm][fn], 0, 0, 0);
                    accRe[fm][fn] = __builtin_amdgcn_mfma_f32_16x16x32_f16(fb[fm], fs.v,  accRe[fm][fn], 0, 0, 0);
                    accIm[fm][fn] = __builtin_amdgcn_mfma_f32_16x16x32_f16(fb[fm], fc.v,  accIm[fm][fn], 0, 0, 0);
                    accIm[fm][fn] = __builtin_amdgcn_mfma_f32_16x16x32_f16(fa[fm], fns.v, accIm[fm][fn], 0, 0, 0);
                }
                // advance base state by Delta-k = 32 (per sub-step)
                c0v[fn] = __builtin_fmaf(c0, C32[fn], -(s0 * S32[fn]));
                s0v[fn] = __builtin_fmaf(s0, C32[fn],  (c0 * S32[fn]));
            }
        }
    }

    // ---- epilogue: out = (re^2 + im^2)/N ----
    // D frag layout (measured m89): col = lane&15, row = (lane>>4)*4 + reg
    const float inv = 1.0f / (float)N_SZ;
    const int orow0 = b0 + ((lane >> 4) << 2);
    const int ocol0 = m0 + wc + (lane & 15);
#pragma unroll
    for (int fm = 0; fm < 4; ++fm)
#pragma unroll
        for (int fn = 0; fn < 4; ++fn) {
            const f32x4 r = accRe[fm][fn];
            const f32x4 im = accIm[fm][fn];
            const int col = ocol0 + fn * 16;
#pragma unroll
            for (int j = 0; j < 4; ++j) {
                const int row = orow0 + fm * 16 + j;
                out[(size_t)row * M_SZ + col] = (r[j] * r[j] + im[j] * im[j]) * inv;
            }
        }
}

extern "C" void kernel_launch(void* const* d_in, const int* in_sizes, int n_in,
                              void* d_out, int out_size, void* d_ws, size_t ws_size,
                              hipStream_t stream) {
    const float* x     = (const float*)d_in[0];
    const float* xgrid = (const float*)d_in[1];
    float* out = (float*)d_out;
    dim3 grid(8 * (M_SZ / MT));   // 8 * 64 = 512 blocks -> 2 per CU
    dim3 block(256);
    periodogram_kernel<<<grid, block, 0, stream>>>(x, xgrid, out);
}

// Round 14
// 65.372 us; speedup vs baseline: 3.0988x; 1.4982x over previous
//
#include <hip/hip_runtime.h>

// Periodogram: out[b,m] = (re^2 + im^2)/N,  re = aC + bS, im = bC - aS
// r14: BARRIER-FREE main loop. A/B pre-converted to f16 once into d_ws in a
// fragment-tiled layout (1KB tile per (row-block, k-chunk); cell c = g*16+r16
// at c*16 bytes holds row r16, k = g*8..g*8+7). Main kernel loads fragments
// directly global->VGPR (lane-linear, L2-resident), trig in registers,
// 64 MFMA/wave-step, NO LDS, NO __syncthreads in the K-loop.

typedef __fp16 half8  __attribute__((ext_vector_type(8)));
typedef __fp16 half2v __attribute__((ext_vector_type(2)));
typedef float  f32x4  __attribute__((ext_vector_type(4)));

#define B_SZ 512
#define N_SZ 1024
#define M_SZ 16384
#define BT 128
#define MT 128
#define KT 32
#define WS_ARR 1048576   // bytes per converted array (512*1024*2)

union U4 { half2v h2[4]; uint4 u; };
union BF { half2v h2[4]; half8 v; uint4 u; };

// ---- pre-kernel: x (f32) -> d_ws (f16, fragment-tiled) ----
__global__ __launch_bounds__(256)
void cvt_kernel(const float* __restrict__ x, unsigned char* __restrict__ ws) {
    const int id  = (int)blockIdx.x * 256 + (int)threadIdx.x;  // 0..131071
    const int arr = id >> 16;            // 0=a, 1=b
    const int rem = id & 65535;
    const int rb  = rem >> 11;           // row block 0..31
    const int kc  = (rem >> 6) & 31;     // k chunk 0..31
    const int l6  = rem & 63;
    const int r16 = l6 >> 2;             // row in block
    const int g   = l6 & 3;              // k sub-group
    const float* src = x + (size_t)(rb * 16 + r16) * 2048 + arr * 1024 + kc * 32 + g * 8;
    const float4 v0 = *(const float4*)src;
    const float4 v1 = *(const float4*)(src + 4);
    U4 u;
    u.h2[0] = __builtin_amdgcn_cvt_pkrtz(v0.x, v0.y);
    u.h2[1] = __builtin_amdgcn_cvt_pkrtz(v0.z, v0.w);
    u.h2[2] = __builtin_amdgcn_cvt_pkrtz(v1.x, v1.y);
    u.h2[3] = __builtin_amdgcn_cvt_pkrtz(v1.z, v1.w);
    *(uint4*)(ws + (size_t)arr * WS_ARR + (size_t)(rb * 32 + kc) * 1024 + (g * 16 + r16) * 16) = u.u;
}

__global__ __launch_bounds__(256, 2)
void periodogram_kernel(const unsigned char* __restrict__ ws,
                        const float* __restrict__ xgrid,
                        float* __restrict__ out) {
    const int tid  = (int)threadIdx.x;
    const int lane = tid & 63;
    const int w    = tid >> 6;
    const int bid  = (int)blockIdx.x;
    const int b0 = (bid & 3) * BT;
    const int m0 = (bid >> 2) * MT;

    const int wr = (w >> 1) * 64;   // wave row offset in tile
    const int wc = (w & 1) * 64;    // wave col offset in tile

    // ---- fragment source pointers (lane-linear within 1KB tiles) ----
    const unsigned char* pA[4];
    const unsigned char* pB[4];
#pragma unroll
    for (int fm = 0; fm < 4; ++fm) {
        const int rb = ((b0 + wr) >> 4) + fm;
        pA[fm] = ws + (size_t)(rb * 32) * 1024 + (size_t)(lane * 16);
        pB[fm] = pA[fm] + WS_ARR;
    }

    // ---- per-lane trig state for the B operand (register-resident) ----
    // lane holds col = wc + fn*16 + (lane&15), k = g8 + j (g8 = (lane>>4)*8),
    // advanced by 32 per K-step. Packed-f16 rotation constants for j=0..7.
    half2v PC[4][4], PS[4][4];
    float c0v[4], s0v[4], C32[4], S32[4];
    const float g8f = (float)((lane >> 4) << 3);
#pragma unroll
    for (int fn = 0; fn < 4; ++fn) {
        const float xg = xgrid[m0 + wc + fn * 16 + (lane & 15)];
        float Cj[8], Sj[8];
        Cj[0] = 1.0f; Sj[0] = 0.0f;
#pragma unroll
        for (int j = 1; j < 8; ++j) {
            float p = xg * (float)j; p -= floorf(p);
            Cj[j] = __builtin_amdgcn_cosf(p);   // cos(2*pi*p)
            Sj[j] = __builtin_amdgcn_sinf(p);
        }
#pragma unroll
        for (int i = 0; i < 4; ++i) {
            PC[fn][i] = __builtin_amdgcn_cvt_pkrtz(Cj[2 * i], Cj[2 * i + 1]);
            PS[fn][i] = __builtin_amdgcn_cvt_pkrtz(Sj[2 * i], Sj[2 * i + 1]);
        }
        float p32 = xg * 32.0f; p32 -= floorf(p32);      // exact product
        C32[fn] = __builtin_amdgcn_cosf(p32);
        S32[fn] = __builtin_amdgcn_sinf(p32);
        float pb = xg * g8f; pb -= floorf(pb);
        c0v[fn] = __builtin_amdgcn_cosf(pb);
        s0v[fn] = __builtin_amdgcn_sinf(pb);
    }

    f32x4 accRe[4][4], accIm[4][4];
#pragma unroll
    for (int i = 0; i < 4; ++i)
#pragma unroll
        for (int j = 0; j < 4; ++j) { accRe[i][j] = (f32x4)0.0f; accIm[i][j] = (f32x4)0.0f; }

    for (int t = 0; t < N_SZ / KT; ++t) {
        // ---- fragment loads: one dwordx4 per (fm, array) from L2 ----
        half8 fa[4], fb[4];
        const unsigned off = (unsigned)(t * 1024);
#pragma unroll
        for (int fm = 0; fm < 4; ++fm) {
            fa[fm] = *(const half8*)(pA[fm] + off);
            fb[fm] = *(const half8*)(pB[fm] + off);
        }
#pragma unroll
        for (int fn = 0; fn < 4; ++fn) {
            const float c0 = c0v[fn], s0 = s0v[fn];
            const half2v c0b = __builtin_amdgcn_cvt_pkrtz(c0, c0);
            const half2v s0b = __builtin_amdgcn_cvt_pkrtz(s0, s0);
            BF fc, fs, fns;
#pragma unroll
            for (int i = 0; i < 4; ++i) {
                fc.h2[i] = c0b * PC[fn][i] - s0b * PS[fn][i];   // pk_mul+pk_fma
                fs.h2[i] = s0b * PC[fn][i] + c0b * PS[fn][i];
            }
            fns.u.x = fs.u.x ^ 0x80008000u;
            fns.u.y = fs.u.y ^ 0x80008000u;
            fns.u.z = fs.u.z ^ 0x80008000u;
            fns.u.w = fs.u.w ^ 0x80008000u;
#pragma unroll
            for (int fm = 0; fm < 4; ++fm) {
                accRe[fm][fn] = __builtin_amdgcn_mfma_f32_16x16x32_f16(fa[fm], fc.v,  accRe[fm][fn], 0, 0, 0);
                accRe[fm][fn] = __builtin_amdgcn_mfma_f32_16x16x32_f16(fb[fm], fs.v,  accRe[fm][fn], 0, 0, 0);
                accIm[fm][fn] = __builtin_amdgcn_mfma_f32_16x16x32_f16(fb[fm], fc.v,  accIm[fm][fn], 0, 0, 0);
                accIm[fm][fn] = __builtin_amdgcn_mfma_f32_16x16x32_f16(fa[fm], fns.v, accIm[fm][fn], 0, 0, 0);
            }
            // advance base state by Delta-k = 32 (f32, depth-2)
            c0v[fn] = __builtin_fmaf(c0, C32[fn], -(s0 * S32[fn]));
            s0v[fn] = __builtin_fmaf(s0, C32[fn],  (c0 * S32[fn]));
        }
    }

    // ---- epilogue: out = (re^2 + im^2)/N ----
    // D frag layout (measured m89): col = lane&15, row = (lane>>4)*4 + reg
    const float inv = 1.0f / (float)N_SZ;
    const int orow0 = b0 + wr + ((lane >> 4) << 2);
    const int ocol0 = m0 + wc + (lane & 15);
#pragma unroll
    for (int fm = 0; fm < 4; ++fm)
#pragma unroll
        for (int fn = 0; fn < 4; ++fn) {
            const f32x4 r = accRe[fm][fn];
            const f32x4 im = accIm[fm][fn];
            const int col = ocol0 + fn * 16;
#pragma unroll
            for (int j = 0; j < 4; ++j) {
                const int row = orow0 + fm * 16 + j;
                out[(size_t)row * M_SZ + col] = (r[j] * r[j] + im[j] * im[j]) * inv;
            }
        }
}

extern "C" void kernel_launch(void* const* d_in, const int* in_sizes, int n_in,
                              void* d_out, int out_size, void* d_ws, size_t ws_size,
                              hipStream_t stream) {
    const float* x     = (const float*)d_in[0];
    const float* xgrid = (const float*)d_in[1];
    float* out = (float*)d_out;
    unsigned char* ws = (unsigned char*)d_ws;
    // pre-convert x -> f16 fragment-tiled (2 MB in d_ws)
    cvt_kernel<<<512, 256, 0, stream>>>(x, ws);
    dim3 grid(B_SZ / BT * (M_SZ / MT));   // 4 * 128 = 512 blocks
    dim3 block(256);
    periodogram_kernel<<<grid, block, 0, stream>>>(ws, xgrid, out);
}